// Round 2
// baseline (622.297 us; speedup 1.0000x reference)
//
#include <hip/hip_runtime.h>
#include <cmath>

#define D_ 4096
#define H_ 32
#define HD_ 128
#define B_ 8
#define MAXSEQ_ 2048
#define AL_ 10
#define FF_ 11008
#define SCALE_ 0.08838834764831845f   // 1/sqrt(128)
#define EPS_ 1e-5f

// ---------- fused: rmsnorm(x) -> xa rows 0..7 ; adapter copy -> xa rows 8..17 ----------
__global__ __launch_bounds__(256) void norm_adapter_k(const float* __restrict__ x,
                                                      const float* __restrict__ w,
                                                      const float* __restrict__ adapter,
                                                      float* __restrict__ xa) {
  int b = blockIdx.x, tid = threadIdx.x;
  if (b < 8) {
    const float* xr = x + (size_t)b * D_;
    float ss = 0.f;
    for (int i = tid; i < D_; i += 256) { float v = xr[i]; ss += v * v; }
    __shared__ float red[256];
    red[tid] = ss; __syncthreads();
    for (int s = 128; s; s >>= 1) { if (tid < s) red[tid] += red[tid + s]; __syncthreads(); }
    float r = rsqrtf(red[0] / (float)D_ + EPS_);
    float* o = xa + (size_t)b * D_;
    for (int i = tid; i < D_; i += 256) o[i] = xr[i] * r * w[i];
  } else {
    int r = b - 8;
    const float4* src = (const float4*)(adapter + (size_t)r * D_);
    float4* dst = (float4*)(xa + (size_t)(8 + r) * D_);
    for (int i = tid; i < D_ / 4; i += 256) dst[i] = src[i];
  }
}

__global__ __launch_bounds__(256) void rmsnorm_k(const float* __restrict__ in,
                                                 const float* __restrict__ w,
                                                 float* __restrict__ out) {
  int b = blockIdx.x, tid = threadIdx.x;
  const float* x = in + (size_t)b * D_;
  float ss = 0.f;
  for (int i = tid; i < D_; i += 256) { float v = x[i]; ss += v * v; }
  __shared__ float red[256];
  red[tid] = ss; __syncthreads();
  for (int s = 128; s; s >>= 1) { if (tid < s) red[tid] += red[tid + s]; __syncthreads(); }
  float r = rsqrtf(red[0] / (float)D_ + EPS_);
  float* o = out + (size_t)b * D_;
  for (int i = tid; i < D_; i += 256) o[i] = x[i] * r * w[i];
}

// ---------------- generic split-K GEMV, float4 columns, HW fp32 atomics ----------------
// X: ROWS x K row-major.  W (per z): K x N row-major.  Y += X @ W.
// grid = (N/1024, K/CHUNK, nmat); block = 256.
template<int ROWS, int CHUNK>
__global__ __launch_bounds__(256) void gemv_atomic(
    const float* __restrict__ X,
    const float* __restrict__ Wa, const float* __restrict__ Wb, const float* __restrict__ Wc,
    float* __restrict__ Ya, float* __restrict__ Yb, float* __restrict__ Yc,
    int N, int K) {
  constexpr int RS = (ROWS + 3) & ~3;            // pad rows to float4 multiple
  const float* W = (blockIdx.z == 0) ? Wa : (blockIdx.z == 1) ? Wb : Wc;
  float*       Y = (blockIdx.z == 0) ? Ya : (blockIdx.z == 1) ? Yb : Yc;
  __shared__ float xs[CHUNK][RS];
  int tid = threadIdx.x;
  int i0 = blockIdx.y * CHUNK;
  for (int idx = tid; idx < ROWS * CHUNK; idx += 256) {
    int r = idx / CHUNK, ii = idx - r * CHUNK;
    xs[ii][r] = X[(size_t)r * K + i0 + ii];
  }
  __syncthreads();
  int N4 = N >> 2;
  int j4 = blockIdx.x * 256 + tid;               // float4 column index
  if (j4 >= N4) return;
  float4 acc[ROWS];
#pragma unroll
  for (int r = 0; r < ROWS; ++r) acc[r] = make_float4(0.f, 0.f, 0.f, 0.f);
  const float4* W4 = (const float4*)W;
  for (int ii = 0; ii < CHUNK; ++ii) {
    float4 w = W4[(size_t)(i0 + ii) * N4 + j4];
    float xr[RS];
#pragma unroll
    for (int q = 0; q < RS / 4; ++q)
      *(float4*)&xr[4 * q] = *(const float4*)&xs[ii][4 * q];
#pragma unroll
    for (int r = 0; r < ROWS; ++r) {
      acc[r].x += xr[r] * w.x; acc[r].y += xr[r] * w.y;
      acc[r].z += xr[r] * w.z; acc[r].w += xr[r] * w.w;
    }
  }
#pragma unroll
  for (int r = 0; r < ROWS; ++r) {
    float* yp = &Y[(size_t)r * N + 4 * j4];
    unsafeAtomicAdd(yp + 0, acc[r].x);
    unsafeAtomicAdd(yp + 1, acc[r].y);
    unsafeAtomicAdd(yp + 2, acc[r].z);
    unsafeAtomicAdd(yp + 3, acc[r].w);
  }
}

// ---------------- RoPE in-place on q (rows 0..7) and new k (rows 0..7) ----------------
__global__ void rope_k(float* __restrict__ qp, float* __restrict__ kp,
                       const float* __restrict__ fc, const float* __restrict__ fs) {
  int tid = blockIdx.x * 256 + threadIdx.x;      // 32768 = 2 tensors * 8b * 2048 pairs
  if (tid >= 32768) return;
  float* buf = (tid & 16384) ? kp : qp;
  int p = tid & 16383;
  int b = p >> 11;
  int rem = p & 2047;
  int h = rem >> 6, i = rem & 63;
  size_t base = (size_t)b * D_ + h * HD_ + 2 * i;
  float a = buf[base], bb = buf[base + 1];
  float c = fc[i], s = fs[i];
  buf[base]     = a * c - bb * s;
  buf[base + 1] = a * s + bb * c;
}

// ---------------- attention pass 1: per (b,h,chunk-of-256) partial ----------------
__global__ __launch_bounds__(256) void attn_partial(
    const float* __restrict__ qp,   // rows 0..7 = q, post-rope
    const float* __restrict__ kp,   // rows 0..7 = new k (post-rope)
    const float* __restrict__ vp,   // rows 0..7 = new v
    const float* __restrict__ ck,   // cache_k (B, 2048, H, HD)
    const float* __restrict__ cv,   // cache_v
    float* __restrict__ part) {     // 2048 x 132: [m, l, pad, pad, o[128]]
  int idx = blockIdx.x;
  int c = idx & 7, bh = idx >> 3;
  int h = bh & 31, b = bh >> 5;
  int tid = threadIdx.x, wave = tid >> 6, lane = tid & 63;
  int half = lane >> 5, l32 = lane & 31;
  __shared__ float sc[256];
  __shared__ float red[256];
  __shared__ float ob[4][128];
  int t0 = c * 256;
  const float4 qv = *(const float4*)&qp[(size_t)b * D_ + h * HD_ + 4 * l32];
  // scores: each wave handles 64 keys as 32 pairs (lane halves)
  for (int i = 0; i < 32; ++i) {
    int tl = wave * 64 + 2 * i + half;
    int t = t0 + tl;
    const float* kptr = (t == MAXSEQ_ - 1)
        ? &kp[(size_t)b * D_ + h * HD_]
        : &ck[(((size_t)b * MAXSEQ_ + t) * H_ + h) * HD_];
    float4 kv = *(const float4*)&kptr[4 * l32];
    float s = qv.x * kv.x + qv.y * kv.y + qv.z * kv.z + qv.w * kv.w;
    s += __shfl_xor(s, 16); s += __shfl_xor(s, 8);
    s += __shfl_xor(s, 4);  s += __shfl_xor(s, 2); s += __shfl_xor(s, 1);
    if (l32 == 0) sc[tl] = s * SCALE_;
  }
  __syncthreads();
  // chunk softmax (partial m, l)
  float sv = sc[tid];
  red[tid] = sv; __syncthreads();
  for (int s = 128; s; s >>= 1) { if (tid < s) red[tid] = fmaxf(red[tid], red[tid + s]); __syncthreads(); }
  float m = red[0]; __syncthreads();
  float p = __expf(sv - m);
  sc[tid] = p;
  red[tid] = p; __syncthreads();
  for (int s = 128; s; s >>= 1) { if (tid < s) red[tid] += red[tid + s]; __syncthreads(); }
  float l = red[0];
  // o = sum p_t * v_t : pairs of keys per wave-iter, float4 per lane over 32-lane halves
  float4 acc = make_float4(0.f, 0.f, 0.f, 0.f);
  for (int i = 0; i < 32; ++i) {
    int tl = wave * 64 + 2 * i + half;
    int t = t0 + tl;
    const float* vptr = (t == MAXSEQ_ - 1)
        ? &vp[(size_t)b * D_ + h * HD_]
        : &cv[(((size_t)b * MAXSEQ_ + t) * H_ + h) * HD_];
    float4 vv = *(const float4*)&vptr[4 * l32];
    float pp = sc[tl];
    acc.x += pp * vv.x; acc.y += pp * vv.y; acc.z += pp * vv.z; acc.w += pp * vv.w;
  }
  acc.x += __shfl_xor(acc.x, 32); acc.y += __shfl_xor(acc.y, 32);
  acc.z += __shfl_xor(acc.z, 32); acc.w += __shfl_xor(acc.w, 32);
  if (half == 0) {
    ob[wave][4 * l32 + 0] = acc.x; ob[wave][4 * l32 + 1] = acc.y;
    ob[wave][4 * l32 + 2] = acc.z; ob[wave][4 * l32 + 3] = acc.w;
  }
  __syncthreads();
  float* po = &part[(size_t)idx * 132];
  if (tid == 0) { po[0] = m; po[1] = l; }
  if (tid < 128) po[4 + tid] = ob[0][tid] + ob[1][tid] + ob[2][tid] + ob[3][tid];
}

// ------- attention pass 2: combine chunks + adapter attention + gate ; also h=x -------
__global__ __launch_bounds__(128) void attn_combine(
    const float* __restrict__ part,
    const float* __restrict__ qp,
    const float* __restrict__ kvk,  // rows 8..17 = ak
    const float* __restrict__ kvv,  // rows 8..17 = av
    const float* __restrict__ gate,
    const float* __restrict__ x,
    float* __restrict__ attn,
    float* __restrict__ hbuf) {
  int bh = blockIdx.x;
  int h = bh & 31, b = bh >> 5;
  int tid = threadIdx.x;            // = d in [0,128)
  const float* pb = &part[(size_t)bh * 8 * 132];
  float mc[8], lc[8];
  float M = -INFINITY;
  for (int c = 0; c < 8; ++c) { mc[c] = pb[c * 132]; lc[c] = pb[c * 132 + 1]; M = fmaxf(M, mc[c]); }
  float L = 0.f, O = 0.f;
  for (int c = 0; c < 8; ++c) {
    float e = __expf(mc[c] - M);
    L += e * lc[c];
    O += e * pb[c * 132 + 4 + tid];
  }
  float main_out = O / L;
  // adapter attention (10 keys, no rope)
  float qd = qp[(size_t)b * D_ + h * HD_ + tid];
  __shared__ float red[128];
  __shared__ float sa[10];
  for (int j = 0; j < 10; ++j) {
    float prod = qd * kvk[(size_t)(8 + j) * D_ + h * HD_ + tid];
    red[tid] = prod; __syncthreads();
    for (int s = 64; s; s >>= 1) { if (tid < s) red[tid] += red[tid + s]; __syncthreads(); }
    if (tid == 0) sa[j] = red[0] * SCALE_;
    __syncthreads();
  }
  float ma = -INFINITY;
  for (int j = 0; j < 10; ++j) ma = fmaxf(ma, sa[j]);
  float la = 0.f, pj[10];
  for (int j = 0; j < 10; ++j) { pj[j] = __expf(sa[j] - ma); la += pj[j]; }
  float ao = 0.f;
  for (int j = 0; j < 10; ++j) ao += pj[j] * kvv[(size_t)(8 + j) * D_ + h * HD_ + tid];
  ao /= la;
  float g = tanhf(gate[h]);
  size_t oidx = (size_t)b * D_ + h * HD_ + tid;
  attn[oidx] = main_out + g * ao;
  hbuf[oidx] = x[oidx];             // init residual for wo-gemv accumulation
}

// ---------- silu(g1)*g3 -> gb ; also out = hbuf (residual init for w2-gemv) ----------
__global__ void silu_out_k(const float* __restrict__ g1, const float* __restrict__ g3,
                           float* __restrict__ g, const float* __restrict__ hbuf,
                           float* __restrict__ out, int n) {
  int i = blockIdx.x * 256 + threadIdx.x;
  if (i < n) { float a = g1[i]; g[i] = (a / (1.f + __expf(-a))) * g3[i]; }
  if (i < 8 * D_) out[i] = hbuf[i];
}

extern "C" void kernel_launch(void* const* d_in, const int* in_sizes, int n_in,
                              void* d_out, int out_size, void* d_ws, size_t ws_size,
                              hipStream_t stream) {
  (void)in_sizes; (void)n_in; (void)out_size; (void)ws_size;
  const float* x       = (const float*)d_in[0];
  const float* adapter = (const float*)d_in[1];
  const float* ck      = (const float*)d_in[2];
  const float* cv      = (const float*)d_in[3];
  const float* fc      = (const float*)d_in[4];
  const float* fs      = (const float*)d_in[5];
  const float* wq      = (const float*)d_in[6];
  const float* wk      = (const float*)d_in[7];
  const float* wv      = (const float*)d_in[8];
  const float* wo      = (const float*)d_in[9];
  const float* gate    = (const float*)d_in[10];
  const float* anw     = (const float*)d_in[11];
  const float* fnw     = (const float*)d_in[12];
  const float* w1      = (const float*)d_in[13];
  const float* w2      = (const float*)d_in[14];
  const float* w3      = (const float*)d_in[15];
  float* out = (float*)d_out;

  float* ws   = (float*)d_ws;
  float* xa   = ws;                    // 18*4096
  float* qp   = xa + 18 * D_;          // 18*4096 (rows 0..7 used)
  float* kp   = qp + 18 * D_;          // rows 0..7 = new k, 8..17 = ak
  float* vp   = kp + 18 * D_;          // rows 0..7 = new v, 8..17 = av
  float* part = vp + 18 * D_;          // 2048*132
  float* attn = part + 2048 * 132;     // 8*4096
  float* hbuf = attn + 8 * D_;         // 8*4096
  float* hn   = hbuf + 8 * D_;         // 8*4096
  float* g1   = hn + 8 * D_;           // 8*11008
  float* g3b  = g1 + 8 * FF_;          // 8*11008
  float* gb   = g3b + 8 * FF_;         // 8*11008

  // 1) xa = [rmsnorm(x); adapter]
  norm_adapter_k<<<18, 256, 0, stream>>>(x, anw, adapter, xa);
  // 2) QKV (+adapter K/V) projections
  hipMemsetAsync(qp, 0, (size_t)3 * 18 * D_ * sizeof(float), stream);
  gemv_atomic<18, 128><<<dim3(4, 32, 3), 256, 0, stream>>>(xa, wq, wk, wv, qp, kp, vp, D_, D_);
  // 3) RoPE on q rows 0..7 and new-k rows 0..7
  rope_k<<<128, 256, 0, stream>>>(qp, kp, fc, fs);
  // 4) flash-decode attention over 2048 positions (pos 2047 = new k/v)
  attn_partial<<<2048, 256, 0, stream>>>(qp, kp, vp, ck, cv, part);
  attn_combine<<<256, 128, 0, stream>>>(part, qp, kp, vp, gate, x, attn, hbuf);
  // 5) h = x + attn @ wo
  gemv_atomic<8, 64><<<dim3(4, 64, 1), 256, 0, stream>>>(attn, wo, wo, wo, hbuf, hbuf, hbuf, D_, D_);
  // 6) hn = rmsnorm(h); FFN up+gate
  rmsnorm_k<<<8, 256, 0, stream>>>(hbuf, fnw, hn);
  hipMemsetAsync(g1, 0, (size_t)2 * 8 * FF_ * sizeof(float), stream);
  gemv_atomic<8, 128><<<dim3(11, 32, 2), 256, 0, stream>>>(hn, w1, w3, w3, g1, g3b, g3b, FF_, D_);
  silu_out_k<<<(8 * FF_ + 255) / 256, 256, 0, stream>>>(g1, g3b, gb, hbuf, out, 8 * FF_);
  // 7) out = h + gb @ w2
  gemv_atomic<8, 86><<<dim3(4, 128, 1), 256, 0, stream>>>(gb, w2, w2, w2, out, out, out, D_, FF_);
}

// Round 3
// 537.030 us; speedup vs baseline: 1.1588x; 1.1588x over previous
//
#include <hip/hip_runtime.h>
#include <cmath>

#define D_ 4096
#define H_ 32
#define HD_ 128
#define B_ 8
#define MAXSEQ_ 2048
#define AL_ 10
#define FF_ 11008
#define SCALE_ 0.08838834764831845f   // 1/sqrt(128)
#define EPS_ 1e-5f

// ---------- fused: rmsnorm(x) -> xa rows 0..7 ; adapter copy -> xa rows 8..17 ----------
__global__ __launch_bounds__(256) void norm_adapter_k(const float* __restrict__ x,
                                                      const float* __restrict__ w,
                                                      const float* __restrict__ adapter,
                                                      float* __restrict__ xa) {
  int b = blockIdx.x, tid = threadIdx.x;
  if (b < 8) {
    const float* xr = x + (size_t)b * D_;
    float ss = 0.f;
    for (int i = tid; i < D_; i += 256) { float v = xr[i]; ss += v * v; }
    __shared__ float red[256];
    red[tid] = ss; __syncthreads();
    for (int s = 128; s; s >>= 1) { if (tid < s) red[tid] += red[tid + s]; __syncthreads(); }
    float r = rsqrtf(red[0] / (float)D_ + EPS_);
    float* o = xa + (size_t)b * D_;
    for (int i = tid; i < D_; i += 256) o[i] = xr[i] * r * w[i];
  } else {
    int r = b - 8;
    const float4* src = (const float4*)(adapter + (size_t)r * D_);
    float4* dst = (float4*)(xa + (size_t)(8 + r) * D_);
    for (int i = tid; i < D_ / 4; i += 256) dst[i] = src[i];
  }
}

__global__ __launch_bounds__(256) void rmsnorm_k(const float* __restrict__ in,
                                                 const float* __restrict__ w,
                                                 float* __restrict__ out) {
  int b = blockIdx.x, tid = threadIdx.x;
  const float* x = in + (size_t)b * D_;
  float ss = 0.f;
  for (int i = tid; i < D_; i += 256) { float v = x[i]; ss += v * v; }
  __shared__ float red[256];
  red[tid] = ss; __syncthreads();
  for (int s = 128; s; s >>= 1) { if (tid < s) red[tid] += red[tid + s]; __syncthreads(); }
  float r = rsqrtf(red[0] / (float)D_ + EPS_);
  float* o = out + (size_t)b * D_;
  for (int i = tid; i < D_; i += 256) o[i] = x[i] * r * w[i];
}

// ------------- split-K GEMV, float4 columns, NO atomics: per-chunk partials -------------
// X: ROWS x K row-major. W (per z): K x N row-major.
// P[((z*gridDim.y + chunk)*ROWS + r)*N + col] = partial sums.
// grid = (N/4/TPB, K/CHUNK, nmat); block = TPB.
template<int ROWS, int CHUNK, int TPB>
__global__ __launch_bounds__(TPB, 1) void gemv_part(
    const float* __restrict__ X,
    const float* __restrict__ Wa, const float* __restrict__ Wb, const float* __restrict__ Wc,
    float* __restrict__ P, int N, int K) {
  constexpr int RS = (ROWS + 3) & ~3;
  const float* W = (blockIdx.z == 0) ? Wa : (blockIdx.z == 1) ? Wb : Wc;
  __shared__ float xs[CHUNK][RS];
  int tid = threadIdx.x;
  int i0 = blockIdx.y * CHUNK;
  for (int idx = tid; idx < ROWS * CHUNK; idx += TPB) {
    int r = idx / CHUNK, ii = idx - r * CHUNK;
    xs[ii][r] = X[(size_t)r * K + i0 + ii];
  }
  __syncthreads();
  int N4 = N >> 2;
  int j4 = blockIdx.x * TPB + tid;
  if (j4 >= N4) return;
  float4 acc[ROWS];
#pragma unroll
  for (int r = 0; r < ROWS; ++r) acc[r] = make_float4(0.f, 0.f, 0.f, 0.f);
  const float4* W4 = (const float4*)W;
  for (int ii = 0; ii < CHUNK; ++ii) {
    float4 w = W4[(size_t)(i0 + ii) * N4 + j4];
    float xr[RS];
#pragma unroll
    for (int q = 0; q < RS / 4; ++q)
      *(float4*)&xr[4 * q] = *(const float4*)&xs[ii][4 * q];
#pragma unroll
    for (int r = 0; r < ROWS; ++r) {
      acc[r].x += xr[r] * w.x; acc[r].y += xr[r] * w.y;
      acc[r].z += xr[r] * w.z; acc[r].w += xr[r] * w.w;
    }
  }
  size_t pb = ((size_t)blockIdx.z * gridDim.y + blockIdx.y) * ROWS;
#pragma unroll
  for (int r = 0; r < ROWS; ++r)
    *(float4*)&P[(pb + r) * N + 4 * j4] = acc[r];
}

// ------- QKV reduction over 16 chunks + fused RoPE on q,k rows 0..7 -------
// P: [z(3)][chunk(16)][row(18)][4096]; out z=0->Ya(q), 1->Yb(k), 2->Yc(v)
__global__ __launch_bounds__(256) void reduce3_rope_k(
    const float* __restrict__ P, const float* __restrict__ fc, const float* __restrict__ fs,
    float* __restrict__ Ya, float* __restrict__ Yb, float* __restrict__ Yc) {
  int z = blockIdx.z;
  int i4 = blockIdx.x * 256 + threadIdx.x;      // 18432 float4 per z
  const float4* P4 = (const float4*)P;
  size_t base = (size_t)z * 16 * 18432 + i4;
  float4 s = make_float4(0.f, 0.f, 0.f, 0.f);
#pragma unroll
  for (int c = 0; c < 16; ++c) {
    float4 v = P4[base + (size_t)c * 18432];
    s.x += v.x; s.y += v.y; s.z += v.z; s.w += v.w;
  }
  int row = i4 >> 10;                            // 1024 float4 per row
  if (z < 2 && row < 8) {                        // rope q,k (not v, not adapter rows)
    int c0 = (i4 & 1023) << 2;
    int p0 = (c0 & 127) >> 1;                    // pair index in head, even
    float ca = fc[p0], sa = fs[p0], cb = fc[p0 + 1], sb = fs[p0 + 1];
    float4 r;
    r.x = s.x * ca - s.y * sa; r.y = s.x * sa + s.y * ca;
    r.z = s.z * cb - s.w * sb; r.w = s.z * sb + s.w * cb;
    s = r;
  }
  float4* Y = (float4*)(z == 0 ? Ya : z == 1 ? Yb : Yc);
  Y[i4] = s;
}

// ------- FFN up/gate reduction: P [z(2)][chunk(16)][row(8)][11008] -------
__global__ __launch_bounds__(256) void reduce2_k(const float* __restrict__ P,
                                                 float* __restrict__ Ya, float* __restrict__ Yb) {
  int z = blockIdx.z;
  int i4 = blockIdx.x * 256 + threadIdx.x;      // 22016 float4 per z
  const float4* P4 = (const float4*)P;
  size_t base = (size_t)z * 16 * 22016 + i4;
  float4 s = make_float4(0.f, 0.f, 0.f, 0.f);
#pragma unroll
  for (int c = 0; c < 16; ++c) {
    float4 v = P4[base + (size_t)c * 22016];
    s.x += v.x; s.y += v.y; s.z += v.z; s.w += v.w;
  }
  float4* Y = (float4*)(z == 0 ? Ya : Yb);
  Y[i4] = s;
}

// ------- generic reduction with residual base: Y = base + sum_c P[c] -------
template<int NC>
__global__ __launch_bounds__(256) void reduceB_k(const float* __restrict__ P,
                                                 const float* __restrict__ base,
                                                 float* __restrict__ Y, int n4) {
  int i4 = blockIdx.x * 256 + threadIdx.x;
  if (i4 >= n4) return;
  const float4* P4 = (const float4*)P;
  float4 s = ((const float4*)base)[i4];
#pragma unroll
  for (int c = 0; c < NC; ++c) {
    float4 v = P4[(size_t)c * n4 + i4];
    s.x += v.x; s.y += v.y; s.z += v.z; s.w += v.w;
  }
  ((float4*)Y)[i4] = s;
}

// ---------------- attention pass 1: per (b,h,chunk-of-256) partial ----------------
__global__ __launch_bounds__(256) void attn_partial(
    const float* __restrict__ qp,   // rows 0..7 = q, post-rope
    const float* __restrict__ kp,   // rows 0..7 = new k (post-rope)
    const float* __restrict__ vp,   // rows 0..7 = new v
    const float* __restrict__ ck,   // cache_k (B, 2048, H, HD)
    const float* __restrict__ cv,   // cache_v
    float* __restrict__ part) {     // 2048 x 132: [m, l, pad, pad, o[128]]
  int idx = blockIdx.x;
  int c = idx & 7, bh = idx >> 3;
  int h = bh & 31, b = bh >> 5;
  int tid = threadIdx.x, wave = tid >> 6, lane = tid & 63;
  int half = lane >> 5, l32 = lane & 31;
  __shared__ float sc[256];
  __shared__ float red[256];
  __shared__ float ob[4][128];
  int t0 = c * 256;
  const float4 qv = *(const float4*)&qp[(size_t)b * D_ + h * HD_ + 4 * l32];
  for (int i = 0; i < 32; ++i) {
    int tl = wave * 64 + 2 * i + half;
    int t = t0 + tl;
    const float* kptr = (t == MAXSEQ_ - 1)
        ? &kp[(size_t)b * D_ + h * HD_]
        : &ck[(((size_t)b * MAXSEQ_ + t) * H_ + h) * HD_];
    float4 kv = *(const float4*)&kptr[4 * l32];
    float s = qv.x * kv.x + qv.y * kv.y + qv.z * kv.z + qv.w * kv.w;
    s += __shfl_xor(s, 16); s += __shfl_xor(s, 8);
    s += __shfl_xor(s, 4);  s += __shfl_xor(s, 2); s += __shfl_xor(s, 1);
    if (l32 == 0) sc[tl] = s * SCALE_;
  }
  __syncthreads();
  float sv = sc[tid];
  red[tid] = sv; __syncthreads();
  for (int s = 128; s; s >>= 1) { if (tid < s) red[tid] = fmaxf(red[tid], red[tid + s]); __syncthreads(); }
  float m = red[0]; __syncthreads();
  float p = __expf(sv - m);
  sc[tid] = p;
  red[tid] = p; __syncthreads();
  for (int s = 128; s; s >>= 1) { if (tid < s) red[tid] += red[tid + s]; __syncthreads(); }
  float l = red[0];
  float4 acc = make_float4(0.f, 0.f, 0.f, 0.f);
  for (int i = 0; i < 32; ++i) {
    int tl = wave * 64 + 2 * i + half;
    int t = t0 + tl;
    const float* vptr = (t == MAXSEQ_ - 1)
        ? &vp[(size_t)b * D_ + h * HD_]
        : &cv[(((size_t)b * MAXSEQ_ + t) * H_ + h) * HD_];
    float4 vv = *(const float4*)&vptr[4 * l32];
    float pp = sc[tl];
    acc.x += pp * vv.x; acc.y += pp * vv.y; acc.z += pp * vv.z; acc.w += pp * vv.w;
  }
  acc.x += __shfl_xor(acc.x, 32); acc.y += __shfl_xor(acc.y, 32);
  acc.z += __shfl_xor(acc.z, 32); acc.w += __shfl_xor(acc.w, 32);
  if (half == 0) {
    ob[wave][4 * l32 + 0] = acc.x; ob[wave][4 * l32 + 1] = acc.y;
    ob[wave][4 * l32 + 2] = acc.z; ob[wave][4 * l32 + 3] = acc.w;
  }
  __syncthreads();
  float* po = &part[(size_t)idx * 132];
  if (tid == 0) { po[0] = m; po[1] = l; }
  if (tid < 128) po[4 + tid] = ob[0][tid] + ob[1][tid] + ob[2][tid] + ob[3][tid];
}

// ------- attention pass 2: combine chunks + adapter attention + gate -------
__global__ __launch_bounds__(128) void attn_combine(
    const float* __restrict__ part,
    const float* __restrict__ qp,
    const float* __restrict__ kvk,  // rows 8..17 = ak
    const float* __restrict__ kvv,  // rows 8..17 = av
    const float* __restrict__ gate,
    float* __restrict__ attn) {
  int bh = blockIdx.x;
  int h = bh & 31, b = bh >> 5;
  int tid = threadIdx.x;            // = d in [0,128)
  const float* pb = &part[(size_t)bh * 8 * 132];
  float mc[8], lc[8];
  float M = -INFINITY;
  for (int c = 0; c < 8; ++c) { mc[c] = pb[c * 132]; lc[c] = pb[c * 132 + 1]; M = fmaxf(M, mc[c]); }
  float L = 0.f, O = 0.f;
  for (int c = 0; c < 8; ++c) {
    float e = __expf(mc[c] - M);
    L += e * lc[c];
    O += e * pb[c * 132 + 4 + tid];
  }
  float main_out = O / L;
  float qd = qp[(size_t)b * D_ + h * HD_ + tid];
  __shared__ float red[128];
  __shared__ float sa[10];
  for (int j = 0; j < 10; ++j) {
    float prod = qd * kvk[(size_t)(8 + j) * D_ + h * HD_ + tid];
    red[tid] = prod; __syncthreads();
    for (int s = 64; s; s >>= 1) { if (tid < s) red[tid] += red[tid + s]; __syncthreads(); }
    if (tid == 0) sa[j] = red[0] * SCALE_;
    __syncthreads();
  }
  float ma = -INFINITY;
  for (int j = 0; j < 10; ++j) ma = fmaxf(ma, sa[j]);
  float la = 0.f, pj[10];
  for (int j = 0; j < 10; ++j) { pj[j] = __expf(sa[j] - ma); la += pj[j]; }
  float ao = 0.f;
  for (int j = 0; j < 10; ++j) ao += pj[j] * kvv[(size_t)(8 + j) * D_ + h * HD_ + tid];
  ao /= la;
  float g = tanhf(gate[h]);
  attn[(size_t)b * D_ + h * HD_ + tid] = main_out + g * ao;
}

// ---------- g1 = silu(g1) * g3 (in place) ----------
__global__ void silu_k(float* __restrict__ g1, const float* __restrict__ g3, int n) {
  int i = blockIdx.x * 256 + threadIdx.x;
  if (i < n) { float a = g1[i]; g1[i] = (a / (1.f + __expf(-a))) * g3[i]; }
}

extern "C" void kernel_launch(void* const* d_in, const int* in_sizes, int n_in,
                              void* d_out, int out_size, void* d_ws, size_t ws_size,
                              hipStream_t stream) {
  (void)in_sizes; (void)n_in; (void)out_size; (void)ws_size;
  const float* x       = (const float*)d_in[0];
  const float* adapter = (const float*)d_in[1];
  const float* ck      = (const float*)d_in[2];
  const float* cv      = (const float*)d_in[3];
  const float* fc      = (const float*)d_in[4];
  const float* fs      = (const float*)d_in[5];
  const float* wq      = (const float*)d_in[6];
  const float* wk      = (const float*)d_in[7];
  const float* wv      = (const float*)d_in[8];
  const float* wo      = (const float*)d_in[9];
  const float* gate    = (const float*)d_in[10];
  const float* anw     = (const float*)d_in[11];
  const float* fnw     = (const float*)d_in[12];
  const float* w1      = (const float*)d_in[13];
  const float* w2      = (const float*)d_in[14];
  const float* w3      = (const float*)d_in[15];
  float* out = (float*)d_out;

  float* ws      = (float*)d_ws;
  float* xa      = ws;                     // 18*4096
  float* qp      = xa + 18 * D_;           // 18*4096 (rows 0..7 valid)
  float* kp      = qp + 18 * D_;           // rows 0..7 = new k (roped), 8..17 = ak
  float* vp      = kp + 18 * D_;           // rows 0..7 = new v, 8..17 = av
  float* attn    = vp + 18 * D_;           // 8*4096
  float* hbuf    = attn + 8 * D_;          // 8*4096
  float* hn      = hbuf + 8 * D_;          // 8*4096
  float* g1      = hn + 8 * D_;            // 8*11008
  float* g3      = g1 + 8 * FF_;           // 8*11008
  float* scratch = g3 + 8 * FF_;           // max phase: 3*16*18*4096 = 3538944 floats
  // phases (time-disjoint, all in `scratch`):
  //   Pqkv 3*16*18*4096 | part 2048*132 | Pwo 32*8*4096 | Pffn 2*16*8*11008 | Pw2 64*8*4096

  // 1) xa = [rmsnorm(x); adapter]
  norm_adapter_k<<<18, 256, 0, stream>>>(x, anw, adapter, xa);
  // 2) QKV (+adapter K/V) projections -> partials -> reduce (+rope on q,k rows 0..7)
  gemv_part<18, 256, 128><<<dim3(8, 16, 3), 128, 0, stream>>>(xa, wq, wk, wv, scratch, D_, D_);
  reduce3_rope_k<<<dim3(72, 1, 3), 256, 0, stream>>>(scratch, fc, fs, qp, kp, vp);
  // 3) flash-decode attention over 2048 positions (pos 2047 = new k/v)
  attn_partial<<<2048, 256, 0, stream>>>(qp, kp, vp, ck, cv, scratch);
  attn_combine<<<256, 128, 0, stream>>>(scratch, qp, kp, vp, gate, attn);
  // 4) h = x + attn @ wo
  gemv_part<8, 128, 128><<<dim3(8, 32, 1), 128, 0, stream>>>(attn, wo, wo, wo, scratch, D_, D_);
  reduceB_k<32><<<32, 256, 0, stream>>>(scratch, x, hbuf, 8192);
  // 5) hn = rmsnorm(h); FFN up+gate
  rmsnorm_k<<<8, 256, 0, stream>>>(hbuf, fnw, hn);
  gemv_part<8, 256, 256><<<dim3(11, 16, 2), 256, 0, stream>>>(hn, w1, w3, w3, scratch, FF_, D_);
  reduce2_k<<<dim3(86, 1, 2), 256, 0, stream>>>(scratch, g1, g3);
  silu_k<<<344, 256, 0, stream>>>(g1, g3, 8 * FF_);
  // 6) out = h + (silu(h@w1)*(h@w3)) @ w2
  gemv_part<8, 172, 256><<<dim3(4, 64, 1), 256, 0, stream>>>(g1, w2, w2, w2, scratch, D_, FF_);
  reduceB_k<64><<<32, 256, 0, stream>>>(scratch, hbuf, out, 8192);
}

// Round 4
// 454.264 us; speedup vs baseline: 1.3699x; 1.1822x over previous
//
#include <hip/hip_runtime.h>
#include <cmath>

#define D_ 4096
#define H_ 32
#define HD_ 128
#define B_ 8
#define MAXSEQ_ 2048
#define AL_ 10
#define FF_ 11008
#define SCALE_ 0.08838834764831845f   // 1/sqrt(128)
#define EPS_ 1e-5f

// ---------- fused: rmsnorm(x) -> xa rows 0..7 ; adapter copy -> xa rows 8..17 ----------
__global__ __launch_bounds__(256) void norm_adapter_k(const float* __restrict__ x,
                                                      const float* __restrict__ w,
                                                      const float* __restrict__ adapter,
                                                      float* __restrict__ xa) {
  int b = blockIdx.x, tid = threadIdx.x;
  if (b < 8) {
    const float* xr = x + (size_t)b * D_;
    float ss = 0.f;
    for (int i = tid; i < D_; i += 256) { float v = xr[i]; ss += v * v; }
    __shared__ float red[256];
    red[tid] = ss; __syncthreads();
    for (int s = 128; s; s >>= 1) { if (tid < s) red[tid] += red[tid + s]; __syncthreads(); }
    float r = rsqrtf(red[0] / (float)D_ + EPS_);
    float* o = xa + (size_t)b * D_;
    for (int i = tid; i < D_; i += 256) o[i] = xr[i] * r * w[i];
  } else {
    int r = b - 8;
    const float4* src = (const float4*)(adapter + (size_t)r * D_);
    float4* dst = (float4*)(xa + (size_t)(8 + r) * D_);
    for (int i = tid; i < D_ / 4; i += 256) dst[i] = src[i];
  }
}

__global__ __launch_bounds__(256) void rmsnorm_k(const float* __restrict__ in,
                                                 const float* __restrict__ w,
                                                 float* __restrict__ out) {
  int b = blockIdx.x, tid = threadIdx.x;
  const float* x = in + (size_t)b * D_;
  float ss = 0.f;
  for (int i = tid; i < D_; i += 256) { float v = x[i]; ss += v * v; }
  __shared__ float red[256];
  red[tid] = ss; __syncthreads();
  for (int s = 128; s; s >>= 1) { if (tid < s) red[tid] += red[tid + s]; __syncthreads(); }
  float r = rsqrtf(red[0] / (float)D_ + EPS_);
  float* o = out + (size_t)b * D_;
  for (int i = tid; i < D_; i += 256) o[i] = x[i] * r * w[i];
}

// ------------- row-split split-K GEMV: 4 waves/block, each wave owns <=NR rows -------------
// All 4 waves cover the SAME 64-float4 column slice (W re-reads hit L1/L2).
// acc per thread = NR float4 (<=20 VGPR) -> no spill. Batched UNROLL loads for MLP.
template<int NR, int ROWS, int CHUNK, int UNROLL>
__device__ __forceinline__ void gemv_core(
    const float4* __restrict__ W4, const float (*xs)[ROWS],
    int i0, int N4, int j4, int r0, float* __restrict__ P, size_t pb, int N) {
  float4 acc[NR];
#pragma unroll
  for (int r = 0; r < NR; ++r) acc[r] = make_float4(0.f, 0.f, 0.f, 0.f);
  for (int iu = 0; iu < CHUNK; iu += UNROLL) {
    float4 w[UNROLL];
#pragma unroll
    for (int u = 0; u < UNROLL; ++u)
      w[u] = W4[(size_t)(i0 + iu + u) * N4 + j4];
#pragma unroll
    for (int u = 0; u < UNROLL; ++u) {
#pragma unroll
      for (int r = 0; r < NR; ++r) {
        float xv = xs[iu + u][r0 + r];
        acc[r].x += xv * w[u].x; acc[r].y += xv * w[u].y;
        acc[r].z += xv * w[u].z; acc[r].w += xv * w[u].w;
      }
    }
  }
#pragma unroll
  for (int r = 0; r < NR; ++r)
    *(float4*)&P[(pb + r) * (size_t)N + (size_t)4 * j4] = acc[r];
}

// grid = (N4/64, K/CHUNK, nmat); block = 256 (4 waves).
// P[((z*gridDim.y + chunk)*ROWS + row)*N + col] = partials.
template<int ROWS, int RPG, int CHUNK, int UNROLL>
__global__ __launch_bounds__(256, 1) void gemv_rs(
    const float* __restrict__ X,
    const float* __restrict__ Wa, const float* __restrict__ Wb, const float* __restrict__ Wc,
    float* __restrict__ P, int N, int K) {
  const float* W = (blockIdx.z == 0) ? Wa : (blockIdx.z == 1) ? Wb : Wc;
  __shared__ float xs[CHUNK][ROWS];
  int tid = threadIdx.x;
  int i0 = blockIdx.y * CHUNK;
  for (int idx = tid; idx < ROWS * CHUNK; idx += 256) {
    int r = idx / CHUNK, ii = idx - r * CHUNK;
    xs[ii][r] = X[(size_t)r * K + i0 + ii];
  }
  __syncthreads();
  int wave = tid >> 6, lane = tid & 63;
  int r0 = wave * RPG;
  int N4 = N >> 2;
  int j4 = blockIdx.x * 64 + lane;              // all N4 here are multiples of 64
  const float4* W4 = (const float4*)W;
  size_t pb = ((size_t)blockIdx.z * gridDim.y + blockIdx.y) * ROWS + r0;
  constexpr int LAST = ROWS - 3 * RPG;          // rows in the last wave's group
  if (r0 + RPG <= ROWS)
    gemv_core<RPG, ROWS, CHUNK, UNROLL>(W4, xs, i0, N4, j4, r0, P, pb, N);
  else if (LAST > 0)
    gemv_core<(LAST > 0 ? LAST : 1), ROWS, CHUNK, UNROLL>(W4, xs, i0, N4, j4, r0, P, pb, N);
}

// ------- QKV reduction over 32 chunks + fused RoPE on q,k rows 0..7 -------
// P: [z(3)][chunk(32)][row(18)][4096]; out z=0->q, 1->k, 2->v
__global__ __launch_bounds__(256) void reduce3_rope_k(
    const float* __restrict__ P, const float* __restrict__ fc, const float* __restrict__ fs,
    float* __restrict__ Ya, float* __restrict__ Yb, float* __restrict__ Yc) {
  int z = blockIdx.z;
  int i4 = blockIdx.x * 256 + threadIdx.x;      // 18432 float4 per z
  const float4* P4 = (const float4*)P;
  size_t base = (size_t)z * 32 * 18432 + i4;
  float4 s = make_float4(0.f, 0.f, 0.f, 0.f);
#pragma unroll 8
  for (int c = 0; c < 32; ++c) {
    float4 v = P4[base + (size_t)c * 18432];
    s.x += v.x; s.y += v.y; s.z += v.z; s.w += v.w;
  }
  int row = i4 >> 10;                            // 1024 float4 per row
  if (z < 2 && row < 8) {                        // rope q,k rows 0..7 only
    int c0 = (i4 & 1023) << 2;
    int p0 = (c0 & 127) >> 1;                    // even pair index in head
    float ca = fc[p0], sa = fs[p0], cb = fc[p0 + 1], sb = fs[p0 + 1];
    float4 r;
    r.x = s.x * ca - s.y * sa; r.y = s.x * sa + s.y * ca;
    r.z = s.z * cb - s.w * sb; r.w = s.z * sb + s.w * cb;
    s = r;
  }
  float4* Y = (float4*)(z == 0 ? Ya : z == 1 ? Yb : Yc);
  Y[i4] = s;
}

// ------- reduction with residual base: Y = base + sum_c P[c] (nc chunks, stride n4) -------
__global__ __launch_bounds__(256) void reduceB_k(const float* __restrict__ P,
                                                 const float* __restrict__ base,
                                                 float* __restrict__ Y, int n4, int nc) {
  int i4 = blockIdx.x * 256 + threadIdx.x;
  if (i4 >= n4) return;
  const float4* P4 = (const float4*)P;
  float4 s = ((const float4*)base)[i4];
  for (int c = 0; c < nc; ++c) {
    float4 v = P4[(size_t)c * n4 + i4];
    s.x += v.x; s.y += v.y; s.z += v.z; s.w += v.w;
  }
  ((float4*)Y)[i4] = s;
}

// ------- FFN: gb = silu(sum P[z=0]) * (sum P[z=1]) ; P [z(2)][chunk(32)][8][11008] -------
__global__ __launch_bounds__(256) void reduce_silu_k(const float* __restrict__ P,
                                                     float* __restrict__ gb) {
  int i4 = blockIdx.x * 256 + threadIdx.x;      // < 22016
  const float4* P4 = (const float4*)P;
  float4 a = make_float4(0.f, 0.f, 0.f, 0.f);
  float4 b = make_float4(0.f, 0.f, 0.f, 0.f);
#pragma unroll 8
  for (int c = 0; c < 32; ++c) {
    float4 u = P4[(size_t)c * 22016 + i4];
    float4 v = P4[(size_t)(32 + c) * 22016 + i4];
    a.x += u.x; a.y += u.y; a.z += u.z; a.w += u.w;
    b.x += v.x; b.y += v.y; b.z += v.z; b.w += v.w;
  }
  float4 o;
  o.x = (a.x / (1.f + __expf(-a.x))) * b.x;
  o.y = (a.y / (1.f + __expf(-a.y))) * b.y;
  o.z = (a.z / (1.f + __expf(-a.z))) * b.z;
  o.w = (a.w / (1.f + __expf(-a.w))) * b.w;
  ((float4*)gb)[i4] = o;
}

// ---------------- attention pass 1: per (b,h,chunk-of-256) partial ----------------
// Pure streaming over the cache; slot t=2047 (chunk 7, tl 255) is masked out and the
// new token is folded in during attn_combine.
__global__ __launch_bounds__(256) void attn_partial(
    const float* __restrict__ qp,   // rows 0..7 = q, post-rope
    const float* __restrict__ ck,   // cache_k (B, 2048, H, HD)
    const float* __restrict__ cv,   // cache_v
    float* __restrict__ part) {     // 2048 x 132: [m, l, pad, pad, o[128]]
  int idx = blockIdx.x;
  int c = idx & 7, bh = idx >> 3;
  int h = bh & 31, b = bh >> 5;
  int tid = threadIdx.x, wave = tid >> 6, lane = tid & 63;
  int half = lane >> 5, l32 = lane & 31;
  bool c7 = (c == 7);
  __shared__ float sc[256];
  __shared__ float red[256];
  __shared__ float ob[4][128];
  int t0 = c * 256;
  const float4 qv = *(const float4*)&qp[(size_t)b * D_ + h * HD_ + 4 * l32];
  for (int i = 0; i < 32; ++i) {
    int tl = wave * 64 + 2 * i + half;
    int t = t0 + tl;
    const float* kptr = &ck[(((size_t)b * MAXSEQ_ + t) * H_ + h) * HD_];
    float4 kv = *(const float4*)&kptr[4 * l32];
    float s = qv.x * kv.x + qv.y * kv.y + qv.z * kv.z + qv.w * kv.w;
    s += __shfl_xor(s, 16); s += __shfl_xor(s, 8);
    s += __shfl_xor(s, 4);  s += __shfl_xor(s, 2); s += __shfl_xor(s, 1);
    if (l32 == 0) sc[tl] = (c7 && tl == 255) ? -1e30f : s * SCALE_;
  }
  __syncthreads();
  float sv = sc[tid];
  red[tid] = sv; __syncthreads();
  for (int s = 128; s; s >>= 1) { if (tid < s) red[tid] = fmaxf(red[tid], red[tid + s]); __syncthreads(); }
  float m = red[0]; __syncthreads();
  float p = __expf(sv - m);
  sc[tid] = p;
  red[tid] = p; __syncthreads();
  for (int s = 128; s; s >>= 1) { if (tid < s) red[tid] += red[tid + s]; __syncthreads(); }
  float l = red[0];
  float4 acc = make_float4(0.f, 0.f, 0.f, 0.f);
  for (int i = 0; i < 32; ++i) {
    int tl = wave * 64 + 2 * i + half;
    int t = t0 + tl;
    const float* vptr = &cv[(((size_t)b * MAXSEQ_ + t) * H_ + h) * HD_];
    float4 vv = *(const float4*)&vptr[4 * l32];
    float pp = sc[tl];                           // 0 for masked slot
    acc.x += pp * vv.x; acc.y += pp * vv.y; acc.z += pp * vv.z; acc.w += pp * vv.w;
  }
  acc.x += __shfl_xor(acc.x, 32); acc.y += __shfl_xor(acc.y, 32);
  acc.z += __shfl_xor(acc.z, 32); acc.w += __shfl_xor(acc.w, 32);
  if (half == 0) {
    ob[wave][4 * l32 + 0] = acc.x; ob[wave][4 * l32 + 1] = acc.y;
    ob[wave][4 * l32 + 2] = acc.z; ob[wave][4 * l32 + 3] = acc.w;
  }
  __syncthreads();
  float* po = &part[(size_t)idx * 132];
  if (tid == 0) { po[0] = m; po[1] = l; }
  if (tid < 128) po[4 + tid] = ob[0][tid] + ob[1][tid] + ob[2][tid] + ob[3][tid];
}

// --- attention pass 2: combine chunks + fold new token + adapter attention + gate ---
__global__ __launch_bounds__(128) void attn_combine(
    const float* __restrict__ part,
    const float* __restrict__ qp,
    const float* __restrict__ kvk,  // rows 0..7 = new k (roped), rows 8..17 = ak
    const float* __restrict__ kvv,  // rows 0..7 = new v,         rows 8..17 = av
    const float* __restrict__ gate,
    float* __restrict__ attn) {
  int bh = blockIdx.x;
  int h = bh & 31, b = bh >> 5;
  int tid = threadIdx.x;            // = d in [0,128)
  const float* pb = &part[(size_t)bh * 8 * 132];
  float mc[8], lc[8];
  float M = -INFINITY;
  for (int c = 0; c < 8; ++c) { mc[c] = pb[c * 132]; lc[c] = pb[c * 132 + 1]; M = fmaxf(M, mc[c]); }
  float L = 0.f, O = 0.f;
  for (int c = 0; c < 8; ++c) {
    float e = __expf(mc[c] - M);
    L += e * lc[c];
    O += e * pb[c * 132 + 4 + tid];
  }
  size_t qi = (size_t)b * D_ + h * HD_ + tid;
  float qd = qp[qi];
  __shared__ float red[128];
  __shared__ float sa[10];
  // new-token score
  red[tid] = qd * kvk[qi]; __syncthreads();
  for (int s = 64; s; s >>= 1) { if (tid < s) red[tid] += red[tid + s]; __syncthreads(); }
  float s_new = red[0] * SCALE_;
  __syncthreads();
  float M2 = fmaxf(M, s_new);
  float eM = __expf(M - M2), eN = __expf(s_new - M2);
  L = L * eM + eN;
  O = O * eM + eN * kvv[qi];
  float main_out = O / L;
  // adapter attention (10 keys, no rope)
  for (int j = 0; j < 10; ++j) {
    float prod = qd * kvk[(size_t)(8 + j) * D_ + h * HD_ + tid];
    red[tid] = prod; __syncthreads();
    for (int s = 64; s; s >>= 1) { if (tid < s) red[tid] += red[tid + s]; __syncthreads(); }
    if (tid == 0) sa[j] = red[0] * SCALE_;
    __syncthreads();
  }
  float ma = -INFINITY;
  for (int j = 0; j < 10; ++j) ma = fmaxf(ma, sa[j]);
  float la = 0.f, pj[10];
  for (int j = 0; j < 10; ++j) { pj[j] = __expf(sa[j] - ma); la += pj[j]; }
  float ao = 0.f;
  for (int j = 0; j < 10; ++j) ao += pj[j] * kvv[(size_t)(8 + j) * D_ + h * HD_ + tid];
  ao /= la;
  float g = tanhf(gate[h]);
  attn[qi] = main_out + g * ao;
}

extern "C" void kernel_launch(void* const* d_in, const int* in_sizes, int n_in,
                              void* d_out, int out_size, void* d_ws, size_t ws_size,
                              hipStream_t stream) {
  (void)in_sizes; (void)n_in; (void)out_size; (void)ws_size;
  const float* x       = (const float*)d_in[0];
  const float* adapter = (const float*)d_in[1];
  const float* ck      = (const float*)d_in[2];
  const float* cv      = (const float*)d_in[3];
  const float* fc      = (const float*)d_in[4];
  const float* fs      = (const float*)d_in[5];
  const float* wq      = (const float*)d_in[6];
  const float* wk      = (const float*)d_in[7];
  const float* wv      = (const float*)d_in[8];
  const float* wo      = (const float*)d_in[9];
  const float* gate    = (const float*)d_in[10];
  const float* anw     = (const float*)d_in[11];
  const float* fnw     = (const float*)d_in[12];
  const float* w1      = (const float*)d_in[13];
  const float* w2      = (const float*)d_in[14];
  const float* w3      = (const float*)d_in[15];
  float* out = (float*)d_out;

  float* ws      = (float*)d_ws;
  float* xa      = ws;                     // 18*4096
  float* qp      = xa + 18 * D_;           // 18*4096 (rows 0..7 valid)
  float* kp      = qp + 18 * D_;           // rows 0..7 = new k (roped), 8..17 = ak
  float* vp      = kp + 18 * D_;           // rows 0..7 = new v, 8..17 = av
  float* attn    = vp + 18 * D_;           // 8*4096
  float* hbuf    = attn + 8 * D_;          // 8*4096
  float* hn      = hbuf + 8 * D_;          // 8*4096
  float* gb      = hn + 8 * D_;            // 8*11008
  float* scratch = gb + 8 * FF_;           // max phase: 3*32*18*4096 = 7,077,888 floats
  // scratch phases (time-disjoint): Pqkv 27MB | part 1MB | Pwo 16.8MB | Pffn 22.5MB | Pw2 22.5MB

  // 1) xa = [rmsnorm(x); adapter]
  norm_adapter_k<<<18, 256, 0, stream>>>(x, anw, adapter, xa);
  // 2) QKV (+adapter K/V) projections -> partials -> reduce (+rope on q,k rows 0..7)
  gemv_rs<18, 5, 128, 16><<<dim3(16, 32, 3), 256, 0, stream>>>(xa, wq, wk, wv, scratch, D_, D_);
  reduce3_rope_k<<<dim3(72, 1, 3), 256, 0, stream>>>(scratch, fc, fs, qp, kp, vp);
  // 3) flash-decode attention (cache positions; new token folded in combine)
  attn_partial<<<2048, 256, 0, stream>>>(qp, ck, cv, scratch);
  attn_combine<<<256, 128, 0, stream>>>(scratch, qp, kp, vp, gate, attn);
  // 4) h = x + attn @ wo
  gemv_rs<8, 2, 32, 8><<<dim3(16, 128, 1), 256, 0, stream>>>(attn, wo, wo, wo, scratch, D_, D_);
  reduceB_k<<<32, 256, 0, stream>>>(scratch, x, hbuf, 8192, 128);
  // 5) hn = rmsnorm(h); FFN up+gate -> fused reduce+silu
  rmsnorm_k<<<8, 256, 0, stream>>>(hbuf, fnw, hn);
  gemv_rs<8, 2, 128, 8><<<dim3(43, 32, 2), 256, 0, stream>>>(hn, w1, w3, w3, scratch, FF_, D_);
  reduce_silu_k<<<86, 256, 0, stream>>>(scratch, gb);
  // 6) out = h + gb @ w2
  gemv_rs<8, 2, 64, 8><<<dim3(16, 172, 1), 256, 0, stream>>>(gb, w2, w2, w2, scratch, D_, FF_);
  reduceB_k<<<32, 256, 0, stream>>>(scratch, hbuf, out, 8192, 172);
}

// Round 5
// 398.255 us; speedup vs baseline: 1.5626x; 1.1406x over previous
//
#include <hip/hip_runtime.h>
#include <cmath>

#define D_ 4096
#define H_ 32
#define HD_ 128
#define B_ 8
#define MAXSEQ_ 2048
#define AL_ 10
#define FF_ 11008
#define SCALE_ 0.08838834764831845f   // 1/sqrt(128)
#define EPS_ 1e-5f

// ---------- fused: rmsnorm(x) -> xa rows 0..7 ; adapter copy -> xa rows 8..17 ----------
__global__ __launch_bounds__(256) void norm_adapter_k(const float* __restrict__ x,
                                                      const float* __restrict__ w,
                                                      const float* __restrict__ adapter,
                                                      float* __restrict__ xa) {
  int b = blockIdx.x, tid = threadIdx.x;
  if (b < 8) {
    const float* xr = x + (size_t)b * D_;
    float ss = 0.f;
    for (int i = tid; i < D_; i += 256) { float v = xr[i]; ss += v * v; }
    __shared__ float red[256];
    red[tid] = ss; __syncthreads();
    for (int s = 128; s; s >>= 1) { if (tid < s) red[tid] += red[tid + s]; __syncthreads(); }
    float r = rsqrtf(red[0] / (float)D_ + EPS_);
    float* o = xa + (size_t)b * D_;
    for (int i = tid; i < D_; i += 256) o[i] = xr[i] * r * w[i];
  } else {
    int r = b - 8;
    const float4* src = (const float4*)(adapter + (size_t)r * D_);
    float4* dst = (float4*)(xa + (size_t)(8 + r) * D_);
    for (int i = tid; i < D_ / 4; i += 256) dst[i] = src[i];
  }
}

__global__ __launch_bounds__(256) void rmsnorm_k(const float* __restrict__ in,
                                                 const float* __restrict__ w,
                                                 float* __restrict__ out) {
  int b = blockIdx.x, tid = threadIdx.x;
  const float* x = in + (size_t)b * D_;
  float ss = 0.f;
  for (int i = tid; i < D_; i += 256) { float v = x[i]; ss += v * v; }
  __shared__ float red[256];
  red[tid] = ss; __syncthreads();
  for (int s = 128; s; s >>= 1) { if (tid < s) red[tid] += red[tid + s]; __syncthreads(); }
  float r = rsqrtf(red[0] / (float)D_ + EPS_);
  float* o = out + (size_t)b * D_;
  for (int i = tid; i < D_; i += 256) o[i] = x[i] * r * w[i];
}

// ------------- row-split split-K GEMV: 4 waves/block, each wave owns <=NR rows -------------
template<int NR, int ROWS, int CHUNK, int UNROLL>
__device__ __forceinline__ void gemv_core(
    const float4* __restrict__ W4, const float (*xs)[ROWS],
    int i0, int N4, int j4, int r0, float* __restrict__ P, size_t pb, int N) {
  float4 acc[NR];
#pragma unroll
  for (int r = 0; r < NR; ++r) acc[r] = make_float4(0.f, 0.f, 0.f, 0.f);
  for (int iu = 0; iu < CHUNK; iu += UNROLL) {
    float4 w[UNROLL];
#pragma unroll
    for (int u = 0; u < UNROLL; ++u)
      w[u] = W4[(size_t)(i0 + iu + u) * N4 + j4];
#pragma unroll
    for (int u = 0; u < UNROLL; ++u) {
#pragma unroll
      for (int r = 0; r < NR; ++r) {
        float xv = xs[iu + u][r0 + r];
        acc[r].x += xv * w[u].x; acc[r].y += xv * w[u].y;
        acc[r].z += xv * w[u].z; acc[r].w += xv * w[u].w;
      }
    }
  }
#pragma unroll
  for (int r = 0; r < NR; ++r)
    *(float4*)&P[(pb + r) * (size_t)N + (size_t)4 * j4] = acc[r];
}

// grid = (N4/64, K/CHUNK, nmat); block = 256 (4 waves).
template<int ROWS, int RPG, int CHUNK, int UNROLL>
__global__ __launch_bounds__(256, 1) void gemv_rs(
    const float* __restrict__ X,
    const float* __restrict__ Wa, const float* __restrict__ Wb, const float* __restrict__ Wc,
    float* __restrict__ P, int N, int K) {
  const float* W = (blockIdx.z == 0) ? Wa : (blockIdx.z == 1) ? Wb : Wc;
  __shared__ float xs[CHUNK][ROWS];
  int tid = threadIdx.x;
  int i0 = blockIdx.y * CHUNK;
  for (int idx = tid; idx < ROWS * CHUNK; idx += 256) {
    int r = idx / CHUNK, ii = idx - r * CHUNK;
    xs[ii][r] = X[(size_t)r * K + i0 + ii];
  }
  __syncthreads();
  int wave = tid >> 6, lane = tid & 63;
  int r0 = wave * RPG;
  int N4 = N >> 2;
  int j4 = blockIdx.x * 64 + lane;
  const float4* W4 = (const float4*)W;
  size_t pb = ((size_t)blockIdx.z * gridDim.y + blockIdx.y) * ROWS + r0;
  constexpr int LAST = ROWS - 3 * RPG;
  if (r0 + RPG <= ROWS)
    gemv_core<RPG, ROWS, CHUNK, UNROLL>(W4, xs, i0, N4, j4, r0, P, pb, N);
  else if (LAST > 0)
    gemv_core<(LAST > 0 ? LAST : 1), ROWS, CHUNK, UNROLL>(W4, xs, i0, N4, j4, r0, P, pb, N);
}

// ------- QKV reduction over 16 chunks + fused RoPE on q,k rows 0..7 -------
// P: [z(3)][chunk(16)][row(18)][4096]
__global__ __launch_bounds__(256) void reduce3_rope_k(
    const float* __restrict__ P, const float* __restrict__ fc, const float* __restrict__ fs,
    float* __restrict__ Ya, float* __restrict__ Yb, float* __restrict__ Yc) {
  int z = blockIdx.z;
  int i4 = blockIdx.x * 256 + threadIdx.x;      // 18432 float4 per z
  const float4* P4 = (const float4*)P;
  size_t base = (size_t)z * 16 * 18432 + i4;
  float4 s = make_float4(0.f, 0.f, 0.f, 0.f);
#pragma unroll
  for (int c = 0; c < 16; ++c) {
    float4 v = P4[base + (size_t)c * 18432];
    s.x += v.x; s.y += v.y; s.z += v.z; s.w += v.w;
  }
  int row = i4 >> 10;
  if (z < 2 && row < 8) {
    int c0 = (i4 & 1023) << 2;
    int p0 = (c0 & 127) >> 1;
    float ca = fc[p0], sa = fs[p0], cb = fc[p0 + 1], sb = fs[p0 + 1];
    float4 r;
    r.x = s.x * ca - s.y * sa; r.y = s.x * sa + s.y * ca;
    r.z = s.z * cb - s.w * sb; r.w = s.z * sb + s.w * cb;
    s = r;
  }
  float4* Y = (float4*)(z == 0 ? Ya : z == 1 ? Yb : Yc);
  Y[i4] = s;
}

// ------- reduction with residual base: Y = base + sum_c P[c] -------
__global__ __launch_bounds__(256) void reduceB_k(const float* __restrict__ P,
                                                 const float* __restrict__ base,
                                                 float* __restrict__ Y, int n4, int nc) {
  int i4 = blockIdx.x * 256 + threadIdx.x;
  if (i4 >= n4) return;
  const float4* P4 = (const float4*)P;
  float4 s = ((const float4*)base)[i4];
  for (int c = 0; c < nc; ++c) {
    float4 v = P4[(size_t)c * n4 + i4];
    s.x += v.x; s.y += v.y; s.z += v.z; s.w += v.w;
  }
  ((float4*)Y)[i4] = s;
}

// ------- FFN: gb = silu(sum P[z=0]) * (sum P[z=1]) ; P [z(2)][chunk(8)][8][11008] -------
__global__ __launch_bounds__(256) void reduce_silu_k(const float* __restrict__ P,
                                                     float* __restrict__ gb) {
  int i4 = blockIdx.x * 256 + threadIdx.x;      // < 22016
  const float4* P4 = (const float4*)P;
  float4 a = make_float4(0.f, 0.f, 0.f, 0.f);
  float4 b = make_float4(0.f, 0.f, 0.f, 0.f);
#pragma unroll
  for (int c = 0; c < 8; ++c) {
    float4 u = P4[(size_t)c * 22016 + i4];
    float4 v = P4[(size_t)(8 + c) * 22016 + i4];
    a.x += u.x; a.y += u.y; a.z += u.z; a.w += u.w;
    b.x += v.x; b.y += v.y; b.z += v.z; b.w += v.w;
  }
  float4 o;
  o.x = (a.x / (1.f + __expf(-a.x))) * b.x;
  o.y = (a.y / (1.f + __expf(-a.y))) * b.y;
  o.z = (a.z / (1.f + __expf(-a.z))) * b.z;
  o.w = (a.w / (1.f + __expf(-a.w))) * b.w;
  ((float4*)gb)[i4] = o;
}

// ---------------- attention pass 1: barrier-free online flash-decode ----------------
// One (b,h,chunk-of-256) per block; each half-wave owns 64 interleaved positions with
// ONLINE softmax (K and V streams both continuously in flight, no __syncthreads).
// Per-wave partial out: part[idx*4 + wave] = [m, l, pad, pad, o[128]].
__global__ __launch_bounds__(256) void attn_partial(
    const float* __restrict__ qp,   // rows 0..7 = q, post-rope
    const float* __restrict__ ck,   // cache_k (B, 2048, H, HD)
    const float* __restrict__ cv,   // cache_v
    float* __restrict__ part) {
  int idx = blockIdx.x;
  int c = idx & 7, bh = idx >> 3;
  int h = bh & 31, b = bh >> 5;
  int tid = threadIdx.x, wave = tid >> 6, lane = tid & 63;
  int half = lane >> 5, l32 = lane & 31;
  int t0 = c * 256 + wave * 64;
  const float4 qv = *(const float4*)&qp[(size_t)b * D_ + h * HD_ + 4 * l32];
  const size_t kvbase = ((size_t)b * MAXSEQ_) * (H_ * HD_) + (size_t)h * HD_ + 4 * l32;
  float m = -INFINITY, l = 0.f;
  float4 o = make_float4(0.f, 0.f, 0.f, 0.f);
#pragma unroll 4
  for (int i = 0; i < 32; ++i) {
    int t = t0 + 2 * i + half;
    size_t off = kvbase + (size_t)t * (H_ * HD_);
    float4 kv = *(const float4*)&ck[off];
    float s = qv.x * kv.x + qv.y * kv.y + qv.z * kv.z + qv.w * kv.w;
    s += __shfl_xor(s, 16); s += __shfl_xor(s, 8);
    s += __shfl_xor(s, 4);  s += __shfl_xor(s, 2); s += __shfl_xor(s, 1);
    s *= SCALE_;
    if (t == MAXSEQ_ - 1) s = -1e30f;     // new token folded in combine
    float mn = fmaxf(m, s);
    float r = __expf(m - mn), p = __expf(s - mn);
    float4 vv = *(const float4*)&cv[off];
    o.x = o.x * r + p * vv.x; o.y = o.y * r + p * vv.y;
    o.z = o.z * r + p * vv.z; o.w = o.w * r + p * vv.w;
    l = l * r + p; m = mn;
  }
  // merge the two 32-lane halves (same d-slice, different position sets)
  float mo = __shfl_xor(m, 32);
  float M = fmaxf(m, mo);
  float e = __expf(m - M);
  o.x *= e; o.y *= e; o.z *= e; o.w *= e; l *= e;
  o.x += __shfl_xor(o.x, 32); o.y += __shfl_xor(o.y, 32);
  o.z += __shfl_xor(o.z, 32); o.w += __shfl_xor(o.w, 32);
  l += __shfl_xor(l, 32);
  float* po = &part[((size_t)idx * 4 + wave) * 132];
  if (lane == 0) { po[0] = M; po[1] = l; }
  if (half == 0) *(float4*)&po[4 + 4 * l32] = o;
}

// --- attention pass 2: combine 32 partials + fold new token + adapter attention + gate ---
__global__ __launch_bounds__(128) void attn_combine(
    const float* __restrict__ part,
    const float* __restrict__ qp,
    const float* __restrict__ kvk,  // rows 0..7 = new k (roped), rows 8..17 = ak
    const float* __restrict__ kvv,  // rows 0..7 = new v,         rows 8..17 = av
    const float* __restrict__ gate,
    float* __restrict__ attn) {
  int bh = blockIdx.x;
  int h = bh & 31, b = bh >> 5;
  int tid = threadIdx.x;            // = d in [0,128)
  const float* pb = &part[(size_t)bh * 32 * 132];
  __shared__ float sm[32], sl[32];
  if (tid < 32) { sm[tid] = pb[tid * 132]; sl[tid] = pb[tid * 132 + 1]; }
  __syncthreads();
  float M = -INFINITY;
  for (int c = 0; c < 32; ++c) M = fmaxf(M, sm[c]);
  float L = 0.f, O = 0.f;
  for (int c = 0; c < 32; ++c) {
    float e = __expf(sm[c] - M);
    L += e * sl[c];
    O += e * pb[c * 132 + 4 + tid];
  }
  size_t qi = (size_t)b * D_ + h * HD_ + tid;
  float qd = qp[qi];
  __shared__ float red[128];
  __shared__ float sa[10];
  // new-token score
  red[tid] = qd * kvk[qi]; __syncthreads();
  for (int s = 64; s; s >>= 1) { if (tid < s) red[tid] += red[tid + s]; __syncthreads(); }
  float s_new = red[0] * SCALE_;
  __syncthreads();
  float M2 = fmaxf(M, s_new);
  float eM = __expf(M - M2), eN = __expf(s_new - M2);
  L = L * eM + eN;
  O = O * eM + eN * kvv[qi];
  float main_out = O / L;
  // adapter attention (10 keys, no rope)
  for (int j = 0; j < 10; ++j) {
    float prod = qd * kvk[(size_t)(8 + j) * D_ + h * HD_ + tid];
    red[tid] = prod; __syncthreads();
    for (int s = 64; s; s >>= 1) { if (tid < s) red[tid] += red[tid + s]; __syncthreads(); }
    if (tid == 0) sa[j] = red[0] * SCALE_;
    __syncthreads();
  }
  float ma = -INFINITY;
  for (int j = 0; j < 10; ++j) ma = fmaxf(ma, sa[j]);
  float la = 0.f, pj[10];
  for (int j = 0; j < 10; ++j) { pj[j] = __expf(sa[j] - ma); la += pj[j]; }
  float ao = 0.f;
  for (int j = 0; j < 10; ++j) ao += pj[j] * kvv[(size_t)(8 + j) * D_ + h * HD_ + tid];
  ao /= la;
  float g = tanhf(gate[h]);
  attn[qi] = main_out + g * ao;
}

extern "C" void kernel_launch(void* const* d_in, const int* in_sizes, int n_in,
                              void* d_out, int out_size, void* d_ws, size_t ws_size,
                              hipStream_t stream) {
  (void)in_sizes; (void)n_in; (void)out_size; (void)ws_size;
  const float* x       = (const float*)d_in[0];
  const float* adapter = (const float*)d_in[1];
  const float* ck      = (const float*)d_in[2];
  const float* cv      = (const float*)d_in[3];
  const float* fc      = (const float*)d_in[4];
  const float* fs      = (const float*)d_in[5];
  const float* wq      = (const float*)d_in[6];
  const float* wk      = (const float*)d_in[7];
  const float* wv      = (const float*)d_in[8];
  const float* wo      = (const float*)d_in[9];
  const float* gate    = (const float*)d_in[10];
  const float* anw     = (const float*)d_in[11];
  const float* fnw     = (const float*)d_in[12];
  const float* w1      = (const float*)d_in[13];
  const float* w2      = (const float*)d_in[14];
  const float* w3      = (const float*)d_in[15];
  float* out = (float*)d_out;

  float* ws      = (float*)d_ws;
  float* xa      = ws;                     // 18*4096
  float* qp      = xa + 18 * D_;           // 18*4096 (rows 0..7 valid)
  float* kp      = qp + 18 * D_;           // rows 0..7 = new k (roped), 8..17 = ak
  float* vp      = kp + 18 * D_;           // rows 0..7 = new v, 8..17 = av
  float* attn    = vp + 18 * D_;           // 8*4096
  float* hbuf    = attn + 8 * D_;          // 8*4096
  float* hn      = hbuf + 8 * D_;          // 8*4096
  float* gb      = hn + 8 * D_;            // 8*11008
  float* scratch = gb + 8 * FF_;           // max phase: 3*16*18*4096 = 3,538,944 floats
  // scratch phases (time-disjoint): Pqkv 13.5MB | part 4.3MB | Pwo 4.2MB | Pffn 5.6MB | Pw2 4.2MB

  // 1) xa = [rmsnorm(x); adapter]
  norm_adapter_k<<<18, 256, 0, stream>>>(x, anw, adapter, xa);
  // 2) QKV (+adapter K/V) projections -> partials -> reduce (+rope q,k rows 0..7)
  gemv_rs<18, 5, 256, 16><<<dim3(16, 16, 3), 256, 0, stream>>>(xa, wq, wk, wv, scratch, D_, D_);
  reduce3_rope_k<<<dim3(72, 1, 3), 256, 0, stream>>>(scratch, fc, fs, qp, kp, vp);
  // 3) barrier-free flash-decode over cache (new token folded in combine)
  attn_partial<<<2048, 256, 0, stream>>>(qp, ck, cv, scratch);
  attn_combine<<<256, 128, 0, stream>>>(scratch, qp, kp, vp, gate, attn);
  // 4) h = x + attn @ wo
  gemv_rs<8, 2, 128, 16><<<dim3(16, 32, 1), 256, 0, stream>>>(attn, wo, wo, wo, scratch, D_, D_);
  reduceB_k<<<32, 256, 0, stream>>>(scratch, x, hbuf, 8192, 32);
  // 5) hn = rmsnorm(h); FFN up+gate -> fused reduce+silu
  rmsnorm_k<<<8, 256, 0, stream>>>(hbuf, fnw, hn);
  gemv_rs<8, 2, 512, 16><<<dim3(43, 8, 2), 256, 0, stream>>>(hn, w1, w3, w3, scratch, FF_, D_);
  reduce_silu_k<<<86, 256, 0, stream>>>(scratch, gb);
  // 6) out = h + gb @ w2
  gemv_rs<8, 2, 344, 8><<<dim3(16, 32, 1), 256, 0, stream>>>(gb, w2, w2, w2, scratch, D_, FF_);
  reduceB_k<<<32, 256, 0, stream>>>(scratch, hbuf, out, 8192, 32);
}